// Round 1
// baseline (872.309 us; speedup 1.0000x reference)
//
#include <hip/hip_runtime.h>
#include <float.h>
#include <math.h>

#define NEG_ATT 0.2f
#define NEG_ACT 0.01f

__device__ __forceinline__ float lrelu(float v, float s) { return v >= 0.f ? v : s * v; }

// ---------------- CSR build ----------------
__global__ void k_init_deg(int* deg, int N) {
  int i = blockIdx.x * blockDim.x + threadIdx.x;
  if (i < N) deg[i] = 1;  // self-loop contributes 1 incoming edge per node
}

__global__ void k_count(const int* __restrict__ ei, int* deg, int E) {
  int e = blockIdx.x * blockDim.x + threadIdx.x;
  if (e < E) atomicAdd(&deg[ei[E + e]], 1);  // row 1 = dst
}

__global__ void k_scan_block(const int* __restrict__ deg, int* row_ptr, int* bsums, int N) {
  __shared__ int tmp[1024];
  int tid = threadIdx.x;
  int i = blockIdx.x * 1024 + tid;
  int v = (i < N) ? deg[i] : 0;
  tmp[tid] = v;
  __syncthreads();
  for (int off = 1; off < 1024; off <<= 1) {
    int t = (tid >= off) ? tmp[tid - off] : 0;
    __syncthreads();
    tmp[tid] += t;
    __syncthreads();
  }
  if (i < N) row_ptr[i] = tmp[tid] - v;  // exclusive within block
  if (tid == 1023) bsums[blockIdx.x] = tmp[tid];
}

__global__ void k_scan_sums(int* bsums, int nb) {
  __shared__ int tmp[256];
  int tid = threadIdx.x;
  int v = (tid < nb) ? bsums[tid] : 0;
  tmp[tid] = v;
  __syncthreads();
  for (int off = 1; off < 256; off <<= 1) {
    int t = (tid >= off) ? tmp[tid - off] : 0;
    __syncthreads();
    tmp[tid] += t;
    __syncthreads();
  }
  if (tid < nb) bsums[tid] = tmp[tid] - v;  // exclusive
  if (tid == 255) bsums[nb] = tmp[255];     // grand total
}

__global__ void k_scan_add(int* row_ptr, const int* __restrict__ bsums, int N, int nb) {
  int i = blockIdx.x * blockDim.x + threadIdx.x;
  if (i < N) row_ptr[i] += bsums[i >> 10];
  else if (i == N) row_ptr[N] = bsums[nb];
}

__global__ void k_copy_cursor(int* cursor, const int* __restrict__ row_ptr, int N) {
  int i = blockIdx.x * blockDim.x + threadIdx.x;
  if (i < N) cursor[i] = row_ptr[i];
}

__global__ void k_scatter(const int* __restrict__ ei, int* cursor, int* col, int E, int N) {
  int t = blockIdx.x * blockDim.x + threadIdx.x;
  if (t >= E + N) return;
  int s, d;
  if (t < E) { s = ei[t]; d = ei[E + t]; }
  else       { s = d = t - E; }  // self-loop
  int pos = atomicAdd(&cursor[d], 1);
  col[pos] = s;
}

// ---------------- GEMM (N x K @ K x 128) + alpha epilogue ----------------
// block = 256 threads, 16 nodes per block. Thread (nl, jg): nl = tid>>4 node,
// jg = tid&15 -> 8 consecutive output cols j0 = jg*8. alpha partials reduced
// across lane pairs (jg^1) to cover a full head (16 cols).
__global__ __launch_bounds__(256) void k_gemm_gat(
    const float* __restrict__ x, const float* __restrict__ W,
    const float* __restrict__ a_src, const float* __restrict__ a_dst,
    float* __restrict__ g, float* __restrict__ as_out, float* __restrict__ ad_out,
    int N, int K, int Kshift) {
  __shared__ float Wl[64 * 128];   // 32 KB: 64 K-rows of W
  __shared__ float xl[16 * 132];   // padded stride KP = K+4 (bank-conflict break)
  const int KP = K + 4;
  int tid = threadIdx.x;
  int n0 = blockIdx.x * 16;

  // stage x tile [16 x K]
  for (int i = tid * 4; i < (K << 4); i += 1024) {
    int row = i >> Kshift;
    int c = i & (K - 1);
    float4 v = make_float4(0.f, 0.f, 0.f, 0.f);
    if (n0 + row < N) v = *(const float4*)(x + (size_t)(n0 + row) * K + c);
    *(float4*)(xl + row * KP + c) = v;
  }

  int nl = tid >> 4, jg = tid & 15, j0 = jg * 8;
  float acc[8] = {0.f, 0.f, 0.f, 0.f, 0.f, 0.f, 0.f, 0.f};
  for (int kb = 0; kb < K; kb += 64) {
    int kc = (K - kb < 64) ? (K - kb) : 64;
    __syncthreads();  // protect Wl reuse + xl visibility on first iter
    for (int i = tid * 4; i < (kc << 7); i += 1024)
      *(float4*)(Wl + i) = *(const float4*)(W + (((size_t)kb) << 7) + i);
    __syncthreads();
    #pragma unroll 4
    for (int kk = 0; kk < kc; ++kk) {
      float xv = xl[nl * KP + kb + kk];
      const float4 w0 = *(const float4*)(Wl + (kk << 7) + j0);
      const float4 w1 = *(const float4*)(Wl + (kk << 7) + j0 + 4);
      acc[0] += xv * w0.x; acc[1] += xv * w0.y; acc[2] += xv * w0.z; acc[3] += xv * w0.w;
      acc[4] += xv * w1.x; acc[5] += xv * w1.y; acc[6] += xv * w1.z; acc[7] += xv * w1.w;
    }
  }
  int n = n0 + nl;
  if (n < N) {
    *(float4*)(g + (size_t)n * 128 + j0)     = make_float4(acc[0], acc[1], acc[2], acc[3]);
    *(float4*)(g + (size_t)n * 128 + j0 + 4) = make_float4(acc[4], acc[5], acc[6], acc[7]);
    int head = jg >> 1, cb = (jg & 1) * 8;
    float ps = 0.f, pd = 0.f;
    #pragma unroll
    for (int t = 0; t < 8; ++t) {
      ps += acc[t] * a_src[head * 16 + cb + t];
      pd += acc[t] * a_dst[head * 16 + cb + t];
    }
    ps += __shfl_xor(ps, 1);
    pd += __shfl_xor(pd, 1);
    if ((jg & 1) == 0) { as_out[n * 8 + head] = ps; ad_out[n * 8 + head] = pd; }
  }
}

// ---------------- aggregation, H=8 C=16 (128 cols) ----------------
// one wave per node. Phase 1: max per head (8 lanes/head strided over edges,
// butterfly reduce). Phase 2 (fused with 3): sequential edge loop, each lane
// owns 2 channels; denominator accumulated redundantly (identical per head).
__global__ __launch_bounds__(256) void k_agg128(
    const int* __restrict__ row_ptr, const int* __restrict__ col,
    const float* __restrict__ as, const float* __restrict__ ad,
    const float* __restrict__ g, const float* __restrict__ bias,
    float* __restrict__ out, int N, int act) {
  int wid = threadIdx.x >> 6;
  int lane = threadIdx.x & 63;
  int n = blockIdx.x * 4 + wid;
  if (n >= N) return;
  int s0 = row_ptr[n], s1 = row_ptr[n + 1];

  int hh = lane & 7, ch = lane >> 3;
  float adv = ad[n * 8 + hh];
  float mx = -FLT_MAX;
  for (int k = s0 + ch; k < s1; k += 8) {
    int s = col[k];
    float e = lrelu(as[s * 8 + hh] + adv, NEG_ATT);
    mx = fmaxf(mx, e);
  }
  #pragma unroll
  for (int off = 8; off < 64; off <<= 1) mx = fmaxf(mx, __shfl_xor(mx, off));

  // phase 3: lane owns channels (2*lane, 2*lane+1); head h3 = lane>>3
  int h3 = lane >> 3;
  float mx3 = __shfl(mx, h3);       // lane h3 holds head-h3 max (h3 & 7 == h3)
  float ad3 = ad[n * 8 + h3];
  float den = 0.f, a0 = 0.f, a1 = 0.f;
  for (int k = s0; k < s1; ++k) {
    int s = col[k];
    float e = lrelu(as[s * 8 + h3] + ad3, NEG_ATT);
    float w = expf(e - mx3);
    den += w;
    const float2 hv = *(const float2*)(g + (size_t)s * 128 + lane * 2);
    a0 += w * hv.x;
    a1 += w * hv.y;
  }
  float inv = 1.f / den;
  float2 bv = *(const float2*)(bias + lane * 2);
  a0 = a0 * inv + bv.x;
  a1 = a1 * inv + bv.y;
  if (act) { a0 = lrelu(a0, NEG_ACT); a1 = lrelu(a1, NEG_ACT); }
  *(float2*)(out + (size_t)n * 128 + lane * 2) = make_float2(a0, a1);
}

// ---------------- decoder: GEMM 128->3 + alphas ----------------
__global__ __launch_bounds__(256) void k_dec_gemm(
    const float* __restrict__ h, const float* __restrict__ Wd,
    const float* __restrict__ asd, const float* __restrict__ add,
    float* __restrict__ g, float* __restrict__ as_out, float* __restrict__ ad_out,
    int N) {
  __shared__ float Wl[384];
  int tid = threadIdx.x;
  for (int i = tid; i < 384; i += 256) Wl[i] = Wd[i];
  __syncthreads();
  int n = blockIdx.x * 256 + tid;
  if (n >= N) return;
  const float* hr = h + (size_t)n * 128;
  float a0 = 0.f, a1 = 0.f, a2 = 0.f;
  #pragma unroll 4
  for (int k = 0; k < 128; k += 4) {
    float4 xv = *(const float4*)(hr + k);
    a0 += xv.x * Wl[k * 3]     + xv.y * Wl[(k + 1) * 3]     + xv.z * Wl[(k + 2) * 3]     + xv.w * Wl[(k + 3) * 3];
    a1 += xv.x * Wl[k * 3 + 1] + xv.y * Wl[(k + 1) * 3 + 1] + xv.z * Wl[(k + 2) * 3 + 1] + xv.w * Wl[(k + 3) * 3 + 1];
    a2 += xv.x * Wl[k * 3 + 2] + xv.y * Wl[(k + 1) * 3 + 2] + xv.z * Wl[(k + 2) * 3 + 2] + xv.w * Wl[(k + 3) * 3 + 2];
  }
  g[(size_t)n * 3]     = a0;
  g[(size_t)n * 3 + 1] = a1;
  g[(size_t)n * 3 + 2] = a2;
  as_out[n] = a0 * asd[0] + a1 * asd[1] + a2 * asd[2];
  ad_out[n] = a0 * add[0] + a1 * add[1] + a2 * add[2];
}

// ---------------- decoder aggregation, H=1 C=3 ----------------
__global__ __launch_bounds__(256) void k_dec_agg(
    const int* __restrict__ row_ptr, const int* __restrict__ col,
    const float* __restrict__ as, const float* __restrict__ ad,
    const float* __restrict__ g, const float* __restrict__ b,
    float* __restrict__ out, int N) {
  int n = blockIdx.x * blockDim.x + threadIdx.x;
  if (n >= N) return;
  int s0 = row_ptr[n], s1 = row_ptr[n + 1];
  float adv = ad[n];
  float mx = -FLT_MAX;
  for (int k = s0; k < s1; ++k) {
    float e = lrelu(as[col[k]] + adv, NEG_ATT);
    mx = fmaxf(mx, e);
  }
  float den = 0.f, a0 = 0.f, a1 = 0.f, a2 = 0.f;
  for (int k = s0; k < s1; ++k) {
    int s = col[k];
    float e = lrelu(as[s] + adv, NEG_ATT);
    float w = expf(e - mx);
    den += w;
    a0 += w * g[(size_t)s * 3];
    a1 += w * g[(size_t)s * 3 + 1];
    a2 += w * g[(size_t)s * 3 + 2];
  }
  float inv = 1.f / den;
  out[(size_t)n * 3]     = a0 * inv + b[0];
  out[(size_t)n * 3 + 1] = a1 * inv + b[1];
  out[(size_t)n * 3 + 2] = a2 * inv + b[2];
}

// ---------------- host ----------------
extern "C" void kernel_launch(void* const* d_in, const int* in_sizes, int n_in,
                              void* d_out, int out_size, void* d_ws, size_t ws_size,
                              hipStream_t stream) {
  const float* x      = (const float*)d_in[0];
  const int*   ei     = (const int*)d_in[1];
  const float* enc_W  = (const float*)d_in[2];
  const float* enc_as = (const float*)d_in[3];
  const float* enc_ad = (const float*)d_in[4];
  const float* enc_b  = (const float*)d_in[5];
  const float* hid_W  = (const float*)d_in[6];
  const float* hid_as = (const float*)d_in[7];
  const float* hid_ad = (const float*)d_in[8];
  const float* hid_b  = (const float*)d_in[9];
  const float* dec_W  = (const float*)d_in[10];
  const float* dec_as = (const float*)d_in[11];
  const float* dec_ad = (const float*)d_in[12];
  const float* dec_b  = (const float*)d_in[13];

  const int N = in_sizes[0] / 16;
  const int E = in_sizes[1] / 2;
  const int L = in_sizes[6] / (128 * 128);

  // workspace layout (floats/ints, 4B units; base assumed 256B-aligned)
  float* hA     = (float*)d_ws;
  float* hB     = hA + (size_t)N * 128;
  float* as_buf = hB + (size_t)N * 128;
  float* ad_buf = as_buf + (size_t)N * 8;
  int*   row_ptr = (int*)(ad_buf + (size_t)N * 8);
  int*   degcur  = row_ptr + (N + 1);       // deg, then reused as scatter cursor
  int*   colb    = degcur + (N + 1);
  int*   bsums   = colb + (E + N);          // up to 257 ints

  const int nb = (N + 1023) / 1024;

  // CSR build
  k_init_deg<<<dim3((N + 255) / 256), dim3(256), 0, stream>>>(degcur, N);
  k_count<<<dim3((E + 255) / 256), dim3(256), 0, stream>>>(ei, degcur, E);
  k_scan_block<<<dim3(nb), dim3(1024), 0, stream>>>(degcur, row_ptr, bsums, N);
  k_scan_sums<<<dim3(1), dim3(256), 0, stream>>>(bsums, nb);
  k_scan_add<<<dim3((N + 256) / 256), dim3(256), 0, stream>>>(row_ptr, bsums, N, nb);
  k_copy_cursor<<<dim3((N + 255) / 256), dim3(256), 0, stream>>>(degcur, row_ptr, N);
  k_scatter<<<dim3((E + N + 255) / 256), dim3(256), 0, stream>>>(ei, degcur, colb, E, N);

  const dim3 gGemm((N + 15) / 16), b256(256);
  const dim3 gAgg((N + 3) / 4);
  const dim3 gNode((N + 255) / 256);

  // encoder (K=16) + leaky_relu(0.01)
  k_gemm_gat<<<gGemm, b256, 0, stream>>>(x, enc_W, enc_as, enc_ad, hB, as_buf, ad_buf, N, 16, 4);
  k_agg128<<<gAgg, b256, 0, stream>>>(row_ptr, colb, as_buf, ad_buf, hB, enc_b, hA, N, 1);

  // hidden layers (K=128)
  for (int l = 0; l < L; ++l) {
    k_gemm_gat<<<gGemm, b256, 0, stream>>>(hA, hid_W + (size_t)l * 128 * 128,
                                           hid_as + (size_t)l * 128, hid_ad + (size_t)l * 128,
                                           hB, as_buf, ad_buf, N, 128, 7);
    k_agg128<<<gAgg, b256, 0, stream>>>(row_ptr, colb, as_buf, ad_buf, hB,
                                        hid_b + (size_t)l * 128, hA, N, 0);
  }

  // decoder
  k_dec_gemm<<<gNode, b256, 0, stream>>>(hA, dec_W, dec_as, dec_ad, hB, as_buf, ad_buf, N);
  k_dec_agg<<<gNode, b256, 0, stream>>>(row_ptr, colb, as_buf, ad_buf, hB, dec_b,
                                        (float*)d_out, N);
}

// Round 2
// 626.460 us; speedup vs baseline: 1.3924x; 1.3924x over previous
//
#include <hip/hip_runtime.h>
#include <float.h>
#include <math.h>

#define NEG_ATT 0.2f
#define NEG_ACT 0.01f
#define MAXD 128   // per-node in-degree cap for LDS logit cache (tail handled)

__device__ __forceinline__ float lrelu(float v, float s) { return v >= 0.f ? v : s * v; }

// ---------------- CSR build ----------------
__global__ void k_init_deg(int* deg, int N) {
  int i = blockIdx.x * blockDim.x + threadIdx.x;
  if (i < N) deg[i] = 1;  // self-loop
}

__global__ void k_count(const int* __restrict__ ei, int* deg, int E) {
  int e = blockIdx.x * blockDim.x + threadIdx.x;
  if (e < E) atomicAdd(&deg[ei[E + e]], 1);  // row 1 = dst
}

__global__ void k_scan_block(const int* __restrict__ deg, int* row_ptr, int* bsums, int N) {
  __shared__ int tmp[1024];
  int tid = threadIdx.x;
  int i = blockIdx.x * 1024 + tid;
  int v = (i < N) ? deg[i] : 0;
  tmp[tid] = v;
  __syncthreads();
  for (int off = 1; off < 1024; off <<= 1) {
    int t = (tid >= off) ? tmp[tid - off] : 0;
    __syncthreads();
    tmp[tid] += t;
    __syncthreads();
  }
  if (i < N) row_ptr[i] = tmp[tid] - v;
  if (tid == 1023) bsums[blockIdx.x] = tmp[tid];
}

__global__ void k_scan_sums(int* bsums, int nb) {
  __shared__ int tmp[256];
  int tid = threadIdx.x;
  int v = (tid < nb) ? bsums[tid] : 0;
  tmp[tid] = v;
  __syncthreads();
  for (int off = 1; off < 256; off <<= 1) {
    int t = (tid >= off) ? tmp[tid - off] : 0;
    __syncthreads();
    tmp[tid] += t;
    __syncthreads();
  }
  if (tid < nb) bsums[tid] = tmp[tid] - v;
  if (tid == 255) bsums[nb] = tmp[255];
}

__global__ void k_scan_add(int* row_ptr, const int* __restrict__ bsums, int N, int nb) {
  int i = blockIdx.x * blockDim.x + threadIdx.x;
  if (i < N) row_ptr[i] += bsums[i >> 10];
  else if (i == N) row_ptr[N] = bsums[nb];
}

__global__ void k_copy_cursor(int* cursor, const int* __restrict__ row_ptr, int N) {
  int i = blockIdx.x * blockDim.x + threadIdx.x;
  if (i < N) cursor[i] = row_ptr[i];
}

__global__ void k_scatter(const int* __restrict__ ei, int* cursor, int* col, int E, int N) {
  int t = blockIdx.x * blockDim.x + threadIdx.x;
  if (t >= E + N) return;
  int s, d;
  if (t < E) { s = ei[t]; d = ei[E + t]; }
  else       { s = d = t - E; }
  int pos = atomicAdd(&cursor[d], 1);
  col[pos] = s;
}

// ---------------- GEMM (N x K @ K x 128) + alpha epilogue, v2 ----------------
// 64 nodes/block, 256 threads. Thread (ng=tid>>4, jg=tid&15) computes 4 nodes
// (ng*4+i) x 8 cols: {jg*4..+3} and {64+jg*4..+3}. The jg*4 column mapping
// makes the Wl ds_read_b128 pattern 2-way bank aliased (free) vs 4-way for
// jg*8. Wl staged in 32-row chunks (16 KB) + xl[64 x (K+4)] (<=33.8 KB).
__global__ __launch_bounds__(256) void k_gemm_gat(
    const float* __restrict__ x, const float* __restrict__ W,
    const float* __restrict__ a_src, const float* __restrict__ a_dst,
    float* __restrict__ g, float* __restrict__ as_out, float* __restrict__ ad_out,
    int N, int K, int Kshift) {
  __shared__ float Wl[32 * 128];      // 16 KB
  __shared__ float xl[64 * 132];      // up to 33.8 KB (K=128 -> KP=132)
  const int KP = K + 4;
  int tid = threadIdx.x;
  int n0 = blockIdx.x * 64;

  // stage x tile [64 x K], zero-fill OOB rows
  for (int i = tid * 4; i < (K << 6); i += 1024) {
    int row = i >> Kshift;
    int c = i & (K - 1);
    float4 v = make_float4(0.f, 0.f, 0.f, 0.f);
    if (n0 + row < N) v = *(const float4*)(x + (size_t)(n0 + row) * K + c);
    *(float4*)(xl + row * KP + c) = v;
  }

  int ng = tid >> 4, jg = tid & 15;
  int jlo = jg * 4, jhi = 64 + jg * 4;
  float alo[4][4] = {}, ahi[4][4] = {};

  for (int kb = 0; kb < K; kb += 32) {
    int kc = (K - kb < 32) ? (K - kb) : 32;
    __syncthreads();
    for (int i = tid * 4; i < (kc << 7); i += 1024)
      *(float4*)(Wl + i) = *(const float4*)(W + (((size_t)kb) << 7) + i);
    __syncthreads();
    #pragma unroll 4
    for (int kk = 0; kk < kc; ++kk) {
      const float4 wlo = *(const float4*)(Wl + (kk << 7) + jlo);
      const float4 whi = *(const float4*)(Wl + (kk << 7) + jhi);
      const float* xr = xl + (ng * 4) * KP + kb + kk;
      #pragma unroll
      for (int i = 0; i < 4; ++i) {
        float xv = xr[i * KP];
        alo[i][0] += xv * wlo.x; alo[i][1] += xv * wlo.y;
        alo[i][2] += xv * wlo.z; alo[i][3] += xv * wlo.w;
        ahi[i][0] += xv * whi.x; ahi[i][1] += xv * whi.y;
        ahi[i][2] += xv * whi.z; ahi[i][3] += xv * whi.w;
      }
    }
  }

  int hlo = jg >> 2, hhi = 4 + (jg >> 2), off4 = (jg & 3) * 4;
  #pragma unroll
  for (int i = 0; i < 4; ++i) {
    int n = n0 + ng * 4 + i;
    if (n >= N) break;
    *(float4*)(g + (size_t)n * 128 + jlo) = make_float4(alo[i][0], alo[i][1], alo[i][2], alo[i][3]);
    *(float4*)(g + (size_t)n * 128 + jhi) = make_float4(ahi[i][0], ahi[i][1], ahi[i][2], ahi[i][3]);
    float ps_lo = 0.f, pd_lo = 0.f, ps_hi = 0.f, pd_hi = 0.f;
    #pragma unroll
    for (int t = 0; t < 4; ++t) {
      ps_lo += alo[i][t] * a_src[hlo * 16 + off4 + t];
      pd_lo += alo[i][t] * a_dst[hlo * 16 + off4 + t];
      ps_hi += ahi[i][t] * a_src[hhi * 16 + off4 + t];
      pd_hi += ahi[i][t] * a_dst[hhi * 16 + off4 + t];
    }
    ps_lo += __shfl_xor(ps_lo, 1); ps_lo += __shfl_xor(ps_lo, 2);
    pd_lo += __shfl_xor(pd_lo, 1); pd_lo += __shfl_xor(pd_lo, 2);
    ps_hi += __shfl_xor(ps_hi, 1); ps_hi += __shfl_xor(ps_hi, 2);
    pd_hi += __shfl_xor(pd_hi, 1); pd_hi += __shfl_xor(pd_hi, 2);
    if ((jg & 3) == 0) {
      as_out[n * 8 + hlo] = ps_lo; ad_out[n * 8 + hlo] = pd_lo;
      as_out[n * 8 + hhi] = ps_hi; ad_out[n * 8 + hhi] = pd_hi;
    }
  }
}

// ---------------- aggregation v2, H=8 C=16 ----------------
// one wave/node. Phase 1: logits e -> LDS (cap MAXD) + per-head max.
// Convert: w = exp(e-m) in LDS + denominator (once, outside hot loop).
// Phase 3: numerator only — col + ds_read(w) + float2 g-gather, unroll x4.
__global__ __launch_bounds__(256) void k_agg128(
    const int* __restrict__ row_ptr, const int* __restrict__ col,
    const float* __restrict__ as, const float* __restrict__ ad,
    const float* __restrict__ g, const float* __restrict__ bias,
    float* __restrict__ out, int N, int act) {
  __shared__ float wbuf[4][MAXD * 8];
  int wid = threadIdx.x >> 6;
  int lane = threadIdx.x & 63;
  float* wp = wbuf[wid];
  int n = blockIdx.x * 4 + wid;
  bool active = n < N;
  int nc = active ? n : 0;
  int s0 = active ? row_ptr[nc] : 0;
  int s1 = active ? row_ptr[nc + 1] : 0;
  int deg = s1 - s0;
  int cap = deg < MAXD ? deg : MAXD;

  // phase 1: lane = (ch=lane>>3 edge-stride, hh=lane&7 head)
  int hh = lane & 7, ch = lane >> 3;
  float adv = ad[nc * 8 + hh];
  float mx = -FLT_MAX;
  for (int k = s0 + ch; k < s1; k += 8) {
    int s = col[k];
    float e = lrelu(as[s * 8 + hh] + adv, NEG_ATT);
    int idx = k - s0;
    if (idx < MAXD) wp[idx * 8 + hh] = e;
    mx = fmaxf(mx, e);
  }
  #pragma unroll
  for (int off = 8; off < 64; off <<= 1) mx = fmaxf(mx, __shfl_xor(mx, off));

  // convert e -> w, accumulate denominator (same-lane LDS reuse, no barrier yet)
  float den = 0.f;
  for (int idx = ch; idx < cap; idx += 8) {
    float w = __expf(wp[idx * 8 + hh] - mx);
    wp[idx * 8 + hh] = w;
    den += w;
  }
  for (int k = s0 + MAXD + ch; k < s1; k += 8) {  // (virtually never taken)
    int s = col[k];
    float e = lrelu(as[s * 8 + hh] + adv, NEG_ATT);
    den += __expf(e - mx);
  }
  #pragma unroll
  for (int off = 8; off < 64; off <<= 1) den += __shfl_xor(den, off);

  __syncthreads();  // wp now read cross-lane

  // phase 3: lane owns channels (2*lane, 2*lane+1); head h3 = lane>>3
  int h3 = lane >> 3;
  float mx3 = __shfl(mx, h3);
  float den3 = __shfl(den, h3);
  float ad3 = ad[nc * 8 + h3];
  float a0 = 0.f, a1 = 0.f;
  int capk = s0 + cap;
  int k = s0;
  const size_t co = (size_t)(lane * 2);
  for (; k + 4 <= capk; k += 4) {
    int sa = col[k], sb = col[k + 1], sc2 = col[k + 2], sd = col[k + 3];
    int i0 = k - s0;
    float wa = wp[i0 * 8 + h3], wb = wp[(i0 + 1) * 8 + h3];
    float wc = wp[(i0 + 2) * 8 + h3], wd = wp[(i0 + 3) * 8 + h3];
    const float2 ha = *(const float2*)(g + (size_t)sa * 128 + co);
    const float2 hb = *(const float2*)(g + (size_t)sb * 128 + co);
    const float2 hc = *(const float2*)(g + (size_t)sc2 * 128 + co);
    const float2 hd = *(const float2*)(g + (size_t)sd * 128 + co);
    a0 += wa * ha.x; a1 += wa * ha.y;
    a0 += wb * hb.x; a1 += wb * hb.y;
    a0 += wc * hc.x; a1 += wc * hc.y;
    a0 += wd * hd.x; a1 += wd * hd.y;
  }
  for (; k < capk; ++k) {
    int s = col[k];
    float w = wp[(k - s0) * 8 + h3];
    const float2 hv = *(const float2*)(g + (size_t)s * 128 + co);
    a0 += w * hv.x; a1 += w * hv.y;
  }
  for (; k < s1; ++k) {  // tail beyond MAXD (virtually never)
    int s = col[k];
    float w = __expf(lrelu(as[s * 8 + h3] + ad3, NEG_ATT) - mx3);
    const float2 hv = *(const float2*)(g + (size_t)s * 128 + co);
    a0 += w * hv.x; a1 += w * hv.y;
  }
  if (active) {
    float inv = 1.f / den3;
    float2 bv = *(const float2*)(bias + co);
    a0 = a0 * inv + bv.x;
    a1 = a1 * inv + bv.y;
    if (act) { a0 = lrelu(a0, NEG_ACT); a1 = lrelu(a1, NEG_ACT); }
    *(float2*)(out + (size_t)n * 128 + co) = make_float2(a0, a1);
  }
}

// ---------------- decoder: GEMM 128->3 + alphas ----------------
__global__ __launch_bounds__(256) void k_dec_gemm(
    const float* __restrict__ h, const float* __restrict__ Wd,
    const float* __restrict__ asd, const float* __restrict__ add,
    float* __restrict__ g, float* __restrict__ as_out, float* __restrict__ ad_out,
    int N) {
  __shared__ float Wl[384];
  int tid = threadIdx.x;
  for (int i = tid; i < 384; i += 256) Wl[i] = Wd[i];
  __syncthreads();
  int n = blockIdx.x * 256 + tid;
  if (n >= N) return;
  const float* hr = h + (size_t)n * 128;
  float a0 = 0.f, a1 = 0.f, a2 = 0.f;
  #pragma unroll 4
  for (int k = 0; k < 128; k += 4) {
    float4 xv = *(const float4*)(hr + k);
    a0 += xv.x * Wl[k * 3]     + xv.y * Wl[(k + 1) * 3]     + xv.z * Wl[(k + 2) * 3]     + xv.w * Wl[(k + 3) * 3];
    a1 += xv.x * Wl[k * 3 + 1] + xv.y * Wl[(k + 1) * 3 + 1] + xv.z * Wl[(k + 2) * 3 + 1] + xv.w * Wl[(k + 3) * 3 + 1];
    a2 += xv.x * Wl[k * 3 + 2] + xv.y * Wl[(k + 1) * 3 + 2] + xv.z * Wl[(k + 2) * 3 + 2] + xv.w * Wl[(k + 3) * 3 + 2];
  }
  g[(size_t)n * 3]     = a0;
  g[(size_t)n * 3 + 1] = a1;
  g[(size_t)n * 3 + 2] = a2;
  as_out[n] = a0 * asd[0] + a1 * asd[1] + a2 * asd[2];
  ad_out[n] = a0 * add[0] + a1 * add[1] + a2 * add[2];
}

// ---------------- decoder aggregation, H=1 C=3 ----------------
__global__ __launch_bounds__(256) void k_dec_agg(
    const int* __restrict__ row_ptr, const int* __restrict__ col,
    const float* __restrict__ as, const float* __restrict__ ad,
    const float* __restrict__ g, const float* __restrict__ b,
    float* __restrict__ out, int N) {
  int n = blockIdx.x * blockDim.x + threadIdx.x;
  if (n >= N) return;
  int s0 = row_ptr[n], s1 = row_ptr[n + 1];
  float adv = ad[n];
  float mx = -FLT_MAX;
  for (int k = s0; k < s1; ++k) {
    float e = lrelu(as[col[k]] + adv, NEG_ATT);
    mx = fmaxf(mx, e);
  }
  float den = 0.f, a0 = 0.f, a1 = 0.f, a2 = 0.f;
  for (int k = s0; k < s1; ++k) {
    int s = col[k];
    float e = lrelu(as[s] + adv, NEG_ATT);
    float w = __expf(e - mx);
    den += w;
    a0 += w * g[(size_t)s * 3];
    a1 += w * g[(size_t)s * 3 + 1];
    a2 += w * g[(size_t)s * 3 + 2];
  }
  float inv = 1.f / den;
  out[(size_t)n * 3]     = a0 * inv + b[0];
  out[(size_t)n * 3 + 1] = a1 * inv + b[1];
  out[(size_t)n * 3 + 2] = a2 * inv + b[2];
}

// ---------------- host ----------------
extern "C" void kernel_launch(void* const* d_in, const int* in_sizes, int n_in,
                              void* d_out, int out_size, void* d_ws, size_t ws_size,
                              hipStream_t stream) {
  const float* x      = (const float*)d_in[0];
  const int*   ei     = (const int*)d_in[1];
  const float* enc_W  = (const float*)d_in[2];
  const float* enc_as = (const float*)d_in[3];
  const float* enc_ad = (const float*)d_in[4];
  const float* enc_b  = (const float*)d_in[5];
  const float* hid_W  = (const float*)d_in[6];
  const float* hid_as = (const float*)d_in[7];
  const float* hid_ad = (const float*)d_in[8];
  const float* hid_b  = (const float*)d_in[9];
  const float* dec_W  = (const float*)d_in[10];
  const float* dec_as = (const float*)d_in[11];
  const float* dec_ad = (const float*)d_in[12];
  const float* dec_b  = (const float*)d_in[13];

  const int N = in_sizes[0] / 16;
  const int E = in_sizes[1] / 2;
  const int L = in_sizes[6] / (128 * 128);

  float* hA     = (float*)d_ws;
  float* hB     = hA + (size_t)N * 128;
  float* as_buf = hB + (size_t)N * 128;
  float* ad_buf = as_buf + (size_t)N * 8;
  int*   row_ptr = (int*)(ad_buf + (size_t)N * 8);
  int*   degcur  = row_ptr + (N + 1);
  int*   colb    = degcur + (N + 1);
  int*   bsums   = colb + (E + N);

  const int nb = (N + 1023) / 1024;

  k_init_deg<<<dim3((N + 255) / 256), dim3(256), 0, stream>>>(degcur, N);
  k_count<<<dim3((E + 255) / 256), dim3(256), 0, stream>>>(ei, degcur, E);
  k_scan_block<<<dim3(nb), dim3(1024), 0, stream>>>(degcur, row_ptr, bsums, N);
  k_scan_sums<<<dim3(1), dim3(256), 0, stream>>>(bsums, nb);
  k_scan_add<<<dim3((N + 256) / 256), dim3(256), 0, stream>>>(row_ptr, bsums, N, nb);
  k_copy_cursor<<<dim3((N + 255) / 256), dim3(256), 0, stream>>>(degcur, row_ptr, N);
  k_scatter<<<dim3((E + N + 255) / 256), dim3(256), 0, stream>>>(ei, degcur, colb, E, N);

  const dim3 gGemm((N + 63) / 64), b256(256);
  const dim3 gAgg((N + 3) / 4);
  const dim3 gNode((N + 255) / 256);

  k_gemm_gat<<<gGemm, b256, 0, stream>>>(x, enc_W, enc_as, enc_ad, hB, as_buf, ad_buf, N, 16, 4);
  k_agg128<<<gAgg, b256, 0, stream>>>(row_ptr, colb, as_buf, ad_buf, hB, enc_b, hA, N, 1);

  for (int l = 0; l < L; ++l) {
    k_gemm_gat<<<gGemm, b256, 0, stream>>>(hA, hid_W + (size_t)l * 128 * 128,
                                           hid_as + (size_t)l * 128, hid_ad + (size_t)l * 128,
                                           hB, as_buf, ad_buf, N, 128, 7);
    k_agg128<<<gAgg, b256, 0, stream>>>(row_ptr, colb, as_buf, ad_buf, hB,
                                        hid_b + (size_t)l * 128, hA, N, 0);
  }

  k_dec_gemm<<<gNode, b256, 0, stream>>>(hA, dec_W, dec_as, dec_ad, hB, as_buf, ad_buf, N);
  k_dec_agg<<<gNode, b256, 0, stream>>>(row_ptr, colb, as_buf, ad_buf, hB, dec_b,
                                        (float*)d_out, N);
}

// Round 3
// 597.597 us; speedup vs baseline: 1.4597x; 1.0483x over previous
//
#include <hip/hip_runtime.h>
#include <float.h>
#include <math.h>

#define NEG_ATT 0.2f
#define NEG_ACT 0.01f
#define MAXD 128   // per-node in-degree cap for LDS logit cache (tail handled)

__device__ __forceinline__ float lrelu(float v, float s) { return v >= 0.f ? v : s * v; }

// ---------------- CSR build ----------------
__global__ void k_init_deg(int* deg, int N) {
  int i = blockIdx.x * blockDim.x + threadIdx.x;
  if (i < N) deg[i] = 1;  // self-loop
}

__global__ void k_count(const int* __restrict__ ei, int* deg, int E) {
  int e = blockIdx.x * blockDim.x + threadIdx.x;
  if (e < E) atomicAdd(&deg[ei[E + e]], 1);  // row 1 = dst
}

__global__ void k_scan_block(const int* __restrict__ deg, int* row_ptr, int* bsums, int N) {
  __shared__ int tmp[1024];
  int tid = threadIdx.x;
  int i = blockIdx.x * 1024 + tid;
  int v = (i < N) ? deg[i] : 0;
  tmp[tid] = v;
  __syncthreads();
  for (int off = 1; off < 1024; off <<= 1) {
    int t = (tid >= off) ? tmp[tid - off] : 0;
    __syncthreads();
    tmp[tid] += t;
    __syncthreads();
  }
  if (i < N) row_ptr[i] = tmp[tid] - v;
  if (tid == 1023) bsums[blockIdx.x] = tmp[tid];
}

__global__ void k_scan_sums(int* bsums, int nb) {
  __shared__ int tmp[256];
  int tid = threadIdx.x;
  int v = (tid < nb) ? bsums[tid] : 0;
  tmp[tid] = v;
  __syncthreads();
  for (int off = 1; off < 256; off <<= 1) {
    int t = (tid >= off) ? tmp[tid - off] : 0;
    __syncthreads();
    tmp[tid] += t;
    __syncthreads();
  }
  if (tid < nb) bsums[tid] = tmp[tid] - v;
  if (tid == 255) bsums[nb] = tmp[255];
}

__global__ void k_scan_add(int* row_ptr, const int* __restrict__ bsums, int N, int nb) {
  int i = blockIdx.x * blockDim.x + threadIdx.x;
  if (i < N) row_ptr[i] += bsums[i >> 10];
  else if (i == N) row_ptr[N] = bsums[nb];
}

__global__ void k_copy_cursor(int* cursor, const int* __restrict__ row_ptr, int N) {
  int i = blockIdx.x * blockDim.x + threadIdx.x;
  if (i < N) cursor[i] = row_ptr[i];
}

__global__ void k_scatter(const int* __restrict__ ei, int* cursor, int* col, int E, int N) {
  int t = blockIdx.x * blockDim.x + threadIdx.x;
  if (t >= E + N) return;
  int s, d;
  if (t < E) { s = ei[t]; d = ei[E + t]; }
  else       { s = d = t - E; }
  int pos = atomicAdd(&cursor[d], 1);
  col[pos] = s;
}

// ---------------- encoder GEMM (N x 16 @ 16 x 128) + alpha epilogue ----------------
__global__ __launch_bounds__(256) void k_gemm_enc(
    const float* __restrict__ x, const float* __restrict__ W,
    const float* __restrict__ a_src, const float* __restrict__ a_dst,
    float* __restrict__ g, float* __restrict__ as_out, float* __restrict__ ad_out,
    int N) {
  const int K = 16, KP = 20;
  __shared__ float Wl[16 * 128];      // 8 KB
  __shared__ float xl[64 * 20];       // 5 KB
  int tid = threadIdx.x;
  int n0 = blockIdx.x * 64;

  for (int i = tid * 4; i < (K << 6); i += 1024) {
    int row = i >> 4;
    int c = i & 15;
    float4 v = make_float4(0.f, 0.f, 0.f, 0.f);
    if (n0 + row < N) v = *(const float4*)(x + (size_t)(n0 + row) * K + c);
    *(float4*)(xl + row * KP + c) = v;
  }
  for (int i = tid * 4; i < 2048; i += 1024)
    *(float4*)(Wl + i) = *(const float4*)(W + i);
  __syncthreads();

  int ng = tid >> 4, jg = tid & 15;
  int jlo = jg * 4, jhi = 64 + jg * 4;
  float alo[4][4] = {}, ahi[4][4] = {};
  #pragma unroll 4
  for (int kk = 0; kk < K; ++kk) {
    const float4 wlo = *(const float4*)(Wl + (kk << 7) + jlo);
    const float4 whi = *(const float4*)(Wl + (kk << 7) + jhi);
    const float* xr = xl + (ng * 4) * KP + kk;
    #pragma unroll
    for (int i = 0; i < 4; ++i) {
      float xv = xr[i * KP];
      alo[i][0] += xv * wlo.x; alo[i][1] += xv * wlo.y;
      alo[i][2] += xv * wlo.z; alo[i][3] += xv * wlo.w;
      ahi[i][0] += xv * whi.x; ahi[i][1] += xv * whi.y;
      ahi[i][2] += xv * whi.z; ahi[i][3] += xv * whi.w;
    }
  }

  int hlo = jg >> 2, hhi = 4 + (jg >> 2), off4 = (jg & 3) * 4;
  #pragma unroll
  for (int i = 0; i < 4; ++i) {
    int n = n0 + ng * 4 + i;
    if (n >= N) break;
    *(float4*)(g + (size_t)n * 128 + jlo) = make_float4(alo[i][0], alo[i][1], alo[i][2], alo[i][3]);
    *(float4*)(g + (size_t)n * 128 + jhi) = make_float4(ahi[i][0], ahi[i][1], ahi[i][2], ahi[i][3]);
    float ps_lo = 0.f, pd_lo = 0.f, ps_hi = 0.f, pd_hi = 0.f;
    #pragma unroll
    for (int t = 0; t < 4; ++t) {
      ps_lo += alo[i][t] * a_src[hlo * 16 + off4 + t];
      pd_lo += alo[i][t] * a_dst[hlo * 16 + off4 + t];
      ps_hi += ahi[i][t] * a_src[hhi * 16 + off4 + t];
      pd_hi += ahi[i][t] * a_dst[hhi * 16 + off4 + t];
    }
    ps_lo += __shfl_xor(ps_lo, 1); ps_lo += __shfl_xor(ps_lo, 2);
    pd_lo += __shfl_xor(pd_lo, 1); pd_lo += __shfl_xor(pd_lo, 2);
    ps_hi += __shfl_xor(ps_hi, 1); ps_hi += __shfl_xor(ps_hi, 2);
    pd_hi += __shfl_xor(pd_hi, 1); pd_hi += __shfl_xor(pd_hi, 2);
    if ((jg & 3) == 0) {
      as_out[n * 8 + hlo] = ps_lo; ad_out[n * 8 + hlo] = pd_lo;
      as_out[n * 8 + hhi] = ps_hi; ad_out[n * 8 + hhi] = pd_hi;
    }
  }
}

// ---------------- hidden GEMM (N x 128 @ 128 x 128), k-major x in LDS ----------------
// 64 nodes/block. Thread (ng=tid>>4, jg=tid&15): 4 nodes x 8 cols (jg*4, 64+jg*4).
// x staged TRANSPOSED (k-major, pad 65) so the a-operand is one ds_read_b128.
// Per kk: 3 x b128 (36 LDS-cyc) vs 32 FMA (64 VALU-cyc) -> VALU-bound.
// jg*4 col mapping => 2-way bank aliasing (free); 24.3 KB LDS -> 6 blocks/CU cap.
__global__ __launch_bounds__(256) void k_gemm_hid(
    const float* __restrict__ x, const float* __restrict__ W,
    const float* __restrict__ a_src, const float* __restrict__ a_dst,
    float* __restrict__ g, float* __restrict__ as_out, float* __restrict__ ad_out,
    int N) {
  __shared__ float xlT[32][65];    // [k][node], 8.3 KB
  __shared__ float Wl[32][128];    // 16 KB
  int tid = threadIdx.x;
  int n0 = blockIdx.x * 64;
  int ng = tid >> 4, jg = tid & 15;
  float acc[4][8] = {};

  for (int kb = 0; kb < 128; kb += 32) {
    __syncthreads();
    // stage W chunk 32x128 (1024 float4, coalesced)
    #pragma unroll
    for (int f = tid; f < 1024; f += 256)
      *(float4*)(&Wl[f >> 5][(f & 31) * 4]) =
          *(const float4*)(W + (size_t)(kb + (f >> 5)) * 128 + (f & 31) * 4);
    // stage x chunk transposed: 64 rows x 32 k
    #pragma unroll
    for (int f = tid; f < 512; f += 256) {
      int row = f >> 3, c = (f & 7) * 4;
      float4 v = make_float4(0.f, 0.f, 0.f, 0.f);
      if (n0 + row < N) v = *(const float4*)(x + (size_t)(n0 + row) * 128 + kb + c);
      xlT[c][row] = v.x; xlT[c + 1][row] = v.y; xlT[c + 2][row] = v.z; xlT[c + 3][row] = v.w;
    }
    __syncthreads();
    #pragma unroll 4
    for (int kk = 0; kk < 32; ++kk) {
      const float4 av  = *(const float4*)(&xlT[kk][ng * 4]);
      const float4 wlo = *(const float4*)(&Wl[kk][jg * 4]);
      const float4 whi = *(const float4*)(&Wl[kk][64 + jg * 4]);
      const float an[4] = {av.x, av.y, av.z, av.w};
      #pragma unroll
      for (int i = 0; i < 4; ++i) {
        acc[i][0] += an[i] * wlo.x; acc[i][1] += an[i] * wlo.y;
        acc[i][2] += an[i] * wlo.z; acc[i][3] += an[i] * wlo.w;
        acc[i][4] += an[i] * whi.x; acc[i][5] += an[i] * whi.y;
        acc[i][6] += an[i] * whi.z; acc[i][7] += an[i] * whi.w;
      }
    }
  }

  int hlo = jg >> 2, hhi = 4 + (jg >> 2), off4 = (jg & 3) * 4;
  int jlo = jg * 4, jhi = 64 + jg * 4;
  #pragma unroll
  for (int i = 0; i < 4; ++i) {
    int n = n0 + ng * 4 + i;
    if (n >= N) break;
    *(float4*)(g + (size_t)n * 128 + jlo) = make_float4(acc[i][0], acc[i][1], acc[i][2], acc[i][3]);
    *(float4*)(g + (size_t)n * 128 + jhi) = make_float4(acc[i][4], acc[i][5], acc[i][6], acc[i][7]);
    float ps_lo = 0.f, pd_lo = 0.f, ps_hi = 0.f, pd_hi = 0.f;
    #pragma unroll
    for (int t = 0; t < 4; ++t) {
      ps_lo += acc[i][t]     * a_src[hlo * 16 + off4 + t];
      pd_lo += acc[i][t]     * a_dst[hlo * 16 + off4 + t];
      ps_hi += acc[i][4 + t] * a_src[hhi * 16 + off4 + t];
      pd_hi += acc[i][4 + t] * a_dst[hhi * 16 + off4 + t];
    }
    ps_lo += __shfl_xor(ps_lo, 1); ps_lo += __shfl_xor(ps_lo, 2);
    pd_lo += __shfl_xor(pd_lo, 1); pd_lo += __shfl_xor(pd_lo, 2);
    ps_hi += __shfl_xor(ps_hi, 1); ps_hi += __shfl_xor(ps_hi, 2);
    pd_hi += __shfl_xor(pd_hi, 1); pd_hi += __shfl_xor(pd_hi, 2);
    if ((jg & 3) == 0) {
      as_out[n * 8 + hlo] = ps_lo; ad_out[n * 8 + hlo] = pd_lo;
      as_out[n * 8 + hhi] = ps_hi; ad_out[n * 8 + hhi] = pd_hi;
    }
  }
}

// ---------------- aggregation v3, H=8 C=16 ----------------
// one wave/node. Phase 1: logits -> LDS + per-head max; convert to w=exp(e-m)
// + denominator. Phase 3: float4 gather — lanes 0-31 even edges, 32-63 odd
// (2 edges / wave-instr, 8 edges in flight), combine via shfl_xor(32).
__global__ __launch_bounds__(256) void k_agg128(
    const int* __restrict__ row_ptr, const int* __restrict__ col,
    const float* __restrict__ as, const float* __restrict__ ad,
    const float* __restrict__ g, const float* __restrict__ bias,
    float* __restrict__ out, int N, int act) {
  __shared__ float wbuf[4][MAXD * 8];
  int wid = threadIdx.x >> 6;
  int lane = threadIdx.x & 63;
  float* wp = wbuf[wid];
  int n = blockIdx.x * 4 + wid;
  bool active = n < N;
  int nc = active ? n : 0;
  int s0 = active ? row_ptr[nc] : 0;
  int s1 = active ? row_ptr[nc + 1] : 0;
  int deg = s1 - s0;
  int cap = deg < MAXD ? deg : MAXD;
  int capk = s0 + cap;

  // phase 1: (ch = lane>>3 edge-stride, hh = lane&7 head)
  int hh = lane & 7, ch = lane >> 3;
  float adv = ad[nc * 8 + hh];
  float mx = -FLT_MAX;
  for (int k = s0 + ch; k < s1; k += 8) {
    int s = col[k];
    float e = lrelu(as[s * 8 + hh] + adv, NEG_ATT);
    int idx = k - s0;
    if (idx < MAXD) wp[idx * 8 + hh] = e;
    mx = fmaxf(mx, e);
  }
  #pragma unroll
  for (int off = 8; off < 64; off <<= 1) mx = fmaxf(mx, __shfl_xor(mx, off));

  float den = 0.f;
  for (int idx = ch; idx < cap; idx += 8) {
    float w = __expf(wp[idx * 8 + hh] - mx);
    wp[idx * 8 + hh] = w;
    den += w;
  }
  for (int k = s0 + MAXD + ch; k < s1; k += 8) {  // beyond-cap (virtually never)
    int s = col[k];
    den += __expf(lrelu(as[s * 8 + hh] + adv, NEG_ATT) - mx);
  }
  #pragma unroll
  for (int off = 8; off < 64; off <<= 1) den += __shfl_xor(den, off);

  __syncthreads();  // wp read cross-lane below

  // phase 3: half-wave per edge-parity; lane owns 4 channels c0..c0+3
  int half = lane >> 5, l32 = lane & 31;
  int c0 = l32 * 4, h4 = l32 >> 2;
  float mx4 = __shfl(mx, h4);
  float den4 = __shfl(den, h4);
  float ad4 = ad[nc * 8 + h4];
  float t0 = 0.f, t1 = 0.f, t2 = 0.f, t3 = 0.f;
  int b = s0;
  for (; b + 8 <= capk; b += 8) {  // 8 edges / wave iter, 4 loads in flight / lane
    int e0 = b + half;
    int sa = col[e0], sb = col[e0 + 2], sc2 = col[e0 + 4], sd = col[e0 + 6];
    float wa = wp[(e0 - s0) * 8 + h4],     wb2 = wp[(e0 + 2 - s0) * 8 + h4];
    float wc = wp[(e0 + 4 - s0) * 8 + h4], wd  = wp[(e0 + 6 - s0) * 8 + h4];
    const float4 ha = *(const float4*)(g + (size_t)sa * 128 + c0);
    const float4 hb = *(const float4*)(g + (size_t)sb * 128 + c0);
    const float4 hc = *(const float4*)(g + (size_t)sc2 * 128 + c0);
    const float4 hd = *(const float4*)(g + (size_t)sd * 128 + c0);
    t0 += wa * ha.x + wb2 * hb.x + wc * hc.x + wd * hd.x;
    t1 += wa * ha.y + wb2 * hb.y + wc * hc.y + wd * hd.y;
    t2 += wa * ha.z + wb2 * hb.z + wc * hc.z + wd * hd.z;
    t3 += wa * ha.w + wb2 * hb.w + wc * hc.w + wd * hd.w;
  }
  for (; b + 4 <= capk; b += 4) {  // 4 edges / wave iter
    int e0 = b + half;
    int sa = col[e0], sb = col[e0 + 2];
    float wa = wp[(e0 - s0) * 8 + h4], wb2 = wp[(e0 + 2 - s0) * 8 + h4];
    const float4 ha = *(const float4*)(g + (size_t)sa * 128 + c0);
    const float4 hb = *(const float4*)(g + (size_t)sb * 128 + c0);
    t0 += wa * ha.x + wb2 * hb.x;
    t1 += wa * ha.y + wb2 * hb.y;
    t2 += wa * ha.z + wb2 * hb.z;
    t3 += wa * ha.w + wb2 * hb.w;
  }
  for (; b < capk; b += 2) {
    int e = b + half;
    if (e < capk) {
      int s = col[e];
      float w = wp[(e - s0) * 8 + h4];
      const float4 hv = *(const float4*)(g + (size_t)s * 128 + c0);
      t0 += w * hv.x; t1 += w * hv.y; t2 += w * hv.z; t3 += w * hv.w;
    }
  }
  for (int k = capk + half; k < s1; k += 2) {  // beyond-cap (virtually never)
    int s = col[k];
    float w = __expf(lrelu(as[s * 8 + h4] + ad4, NEG_ATT) - mx4);
    const float4 hv = *(const float4*)(g + (size_t)s * 128 + c0);
    t0 += w * hv.x; t1 += w * hv.y; t2 += w * hv.z; t3 += w * hv.w;
  }
  t0 += __shfl_xor(t0, 32); t1 += __shfl_xor(t1, 32);
  t2 += __shfl_xor(t2, 32); t3 += __shfl_xor(t3, 32);
  if (active && half == 0) {
    float inv = 1.f / den4;
    const float4 bv = *(const float4*)(bias + c0);
    float o0 = t0 * inv + bv.x, o1 = t1 * inv + bv.y;
    float o2 = t2 * inv + bv.z, o3 = t3 * inv + bv.w;
    if (act) {
      o0 = lrelu(o0, NEG_ACT); o1 = lrelu(o1, NEG_ACT);
      o2 = lrelu(o2, NEG_ACT); o3 = lrelu(o3, NEG_ACT);
    }
    *(float4*)(out + (size_t)n * 128 + c0) = make_float4(o0, o1, o2, o3);
  }
}

// ---------------- decoder: GEMM 128->3 + alphas ----------------
__global__ __launch_bounds__(256) void k_dec_gemm(
    const float* __restrict__ h, const float* __restrict__ Wd,
    const float* __restrict__ asd, const float* __restrict__ add,
    float* __restrict__ g, float* __restrict__ as_out, float* __restrict__ ad_out,
    int N) {
  __shared__ float Wl[384];
  int tid = threadIdx.x;
  for (int i = tid; i < 384; i += 256) Wl[i] = Wd[i];
  __syncthreads();
  int n = blockIdx.x * 256 + tid;
  if (n >= N) return;
  const float* hr = h + (size_t)n * 128;
  float a0 = 0.f, a1 = 0.f, a2 = 0.f;
  #pragma unroll 4
  for (int k = 0; k < 128; k += 4) {
    float4 xv = *(const float4*)(hr + k);
    a0 += xv.x * Wl[k * 3]     + xv.y * Wl[(k + 1) * 3]     + xv.z * Wl[(k + 2) * 3]     + xv.w * Wl[(k + 3) * 3];
    a1 += xv.x * Wl[k * 3 + 1] + xv.y * Wl[(k + 1) * 3 + 1] + xv.z * Wl[(k + 2) * 3 + 1] + xv.w * Wl[(k + 3) * 3 + 1];
    a2 += xv.x * Wl[k * 3 + 2] + xv.y * Wl[(k + 1) * 3 + 2] + xv.z * Wl[(k + 2) * 3 + 2] + xv.w * Wl[(k + 3) * 3 + 2];
  }
  g[(size_t)n * 3]     = a0;
  g[(size_t)n * 3 + 1] = a1;
  g[(size_t)n * 3 + 2] = a2;
  as_out[n] = a0 * asd[0] + a1 * asd[1] + a2 * asd[2];
  ad_out[n] = a0 * add[0] + a1 * add[1] + a2 * add[2];
}

// ---------------- decoder aggregation, H=1 C=3 ----------------
__global__ __launch_bounds__(256) void k_dec_agg(
    const int* __restrict__ row_ptr, const int* __restrict__ col,
    const float* __restrict__ as, const float* __restrict__ ad,
    const float* __restrict__ g, const float* __restrict__ b,
    float* __restrict__ out, int N) {
  int n = blockIdx.x * blockDim.x + threadIdx.x;
  if (n >= N) return;
  int s0 = row_ptr[n], s1 = row_ptr[n + 1];
  float adv = ad[n];
  float mx = -FLT_MAX;
  for (int k = s0; k < s1; ++k) {
    float e = lrelu(as[col[k]] + adv, NEG_ATT);
    mx = fmaxf(mx, e);
  }
  float den = 0.f, a0 = 0.f, a1 = 0.f, a2 = 0.f;
  for (int k = s0; k < s1; ++k) {
    int s = col[k];
    float e = lrelu(as[s] + adv, NEG_ATT);
    float w = __expf(e - mx);
    den += w;
    a0 += w * g[(size_t)s * 3];
    a1 += w * g[(size_t)s * 3 + 1];
    a2 += w * g[(size_t)s * 3 + 2];
  }
  float inv = 1.f / den;
  out[(size_t)n * 3]     = a0 * inv + b[0];
  out[(size_t)n * 3 + 1] = a1 * inv + b[1];
  out[(size_t)n * 3 + 2] = a2 * inv + b[2];
}

// ---------------- host ----------------
extern "C" void kernel_launch(void* const* d_in, const int* in_sizes, int n_in,
                              void* d_out, int out_size, void* d_ws, size_t ws_size,
                              hipStream_t stream) {
  const float* x      = (const float*)d_in[0];
  const int*   ei     = (const int*)d_in[1];
  const float* enc_W  = (const float*)d_in[2];
  const float* enc_as = (const float*)d_in[3];
  const float* enc_ad = (const float*)d_in[4];
  const float* enc_b  = (const float*)d_in[5];
  const float* hid_W  = (const float*)d_in[6];
  const float* hid_as = (const float*)d_in[7];
  const float* hid_ad = (const float*)d_in[8];
  const float* hid_b  = (const float*)d_in[9];
  const float* dec_W  = (const float*)d_in[10];
  const float* dec_as = (const float*)d_in[11];
  const float* dec_ad = (const float*)d_in[12];
  const float* dec_b  = (const float*)d_in[13];

  const int N = in_sizes[0] / 16;
  const int E = in_sizes[1] / 2;
  const int L = in_sizes[6] / (128 * 128);

  float* hA     = (float*)d_ws;
  float* hB     = hA + (size_t)N * 128;
  float* as_buf = hB + (size_t)N * 128;
  float* ad_buf = as_buf + (size_t)N * 8;
  int*   row_ptr = (int*)(ad_buf + (size_t)N * 8);
  int*   degcur  = row_ptr + (N + 1);
  int*   colb    = degcur + (N + 1);
  int*   bsums   = colb + (E + N);

  const int nb = (N + 1023) / 1024;

  k_init_deg<<<dim3((N + 255) / 256), dim3(256), 0, stream>>>(degcur, N);
  k_count<<<dim3((E + 255) / 256), dim3(256), 0, stream>>>(ei, degcur, E);
  k_scan_block<<<dim3(nb), dim3(1024), 0, stream>>>(degcur, row_ptr, bsums, N);
  k_scan_sums<<<dim3(1), dim3(256), 0, stream>>>(bsums, nb);
  k_scan_add<<<dim3((N + 256) / 256), dim3(256), 0, stream>>>(row_ptr, bsums, N, nb);
  k_copy_cursor<<<dim3((N + 255) / 256), dim3(256), 0, stream>>>(degcur, row_ptr, N);
  k_scatter<<<dim3((E + N + 255) / 256), dim3(256), 0, stream>>>(ei, degcur, colb, E, N);

  const dim3 gGemm((N + 63) / 64), b256(256);
  const dim3 gAgg((N + 3) / 4);
  const dim3 gNode((N + 255) / 256);

  k_gemm_enc<<<gGemm, b256, 0, stream>>>(x, enc_W, enc_as, enc_ad, hB, as_buf, ad_buf, N);
  k_agg128<<<gAgg, b256, 0, stream>>>(row_ptr, colb, as_buf, ad_buf, hB, enc_b, hA, N, 1);

  for (int l = 0; l < L; ++l) {
    k_gemm_hid<<<gGemm, b256, 0, stream>>>(hA, hid_W + (size_t)l * 128 * 128,
                                           hid_as + (size_t)l * 128, hid_ad + (size_t)l * 128,
                                           hB, as_buf, ad_buf, N);
    k_agg128<<<gAgg, b256, 0, stream>>>(row_ptr, colb, as_buf, ad_buf, hB,
                                        hid_b + (size_t)l * 128, hA, N, 0);
  }

  k_dec_gemm<<<gNode, b256, 0, stream>>>(hA, dec_W, dec_as, dec_ad, hB, as_buf, ad_buf, N);
  k_dec_agg<<<gNode, b256, 0, stream>>>(row_ptr, colb, as_buf, ad_buf, hB, dec_b,
                                        (float*)d_out, N);
}

// Round 4
// 499.374 us; speedup vs baseline: 1.7468x; 1.1967x over previous
//
#include <hip/hip_runtime.h>
#include <hip/hip_fp16.h>
#include <float.h>
#include <math.h>

#define NEG_ATT 0.2f
#define NEG_ACT 0.01f
#define MAXD 128   // per-node in-degree cap for LDS logit cache (tail handled)

__device__ __forceinline__ float lrelu(float v, float s) { return v >= 0.f ? v : s * v; }

struct __align__(16) H8 { __half2 a, b, c, d; };
struct __align__(8)  H4 { __half2 x, y; };

// ---------------- CSR build ----------------
__global__ void k_init_deg(int* deg, int N) {
  int i = blockIdx.x * blockDim.x + threadIdx.x;
  if (i < N) deg[i] = 1;  // self-loop
}

__global__ void k_count(const int* __restrict__ ei, int* deg, int E) {
  int e = blockIdx.x * blockDim.x + threadIdx.x;
  if (e < E) atomicAdd(&deg[ei[E + e]], 1);  // row 1 = dst
}

__global__ void k_scan_block(const int* __restrict__ deg, int* row_ptr, int* bsums, int N) {
  __shared__ int tmp[1024];
  int tid = threadIdx.x;
  int i = blockIdx.x * 1024 + tid;
  int v = (i < N) ? deg[i] : 0;
  tmp[tid] = v;
  __syncthreads();
  for (int off = 1; off < 1024; off <<= 1) {
    int t = (tid >= off) ? tmp[tid - off] : 0;
    __syncthreads();
    tmp[tid] += t;
    __syncthreads();
  }
  if (i < N) row_ptr[i] = tmp[tid] - v;
  if (tid == 1023) bsums[blockIdx.x] = tmp[tid];
}

__global__ void k_scan_sums(int* bsums, int nb) {
  __shared__ int tmp[256];
  int tid = threadIdx.x;
  int v = (tid < nb) ? bsums[tid] : 0;
  tmp[tid] = v;
  __syncthreads();
  for (int off = 1; off < 256; off <<= 1) {
    int t = (tid >= off) ? tmp[tid - off] : 0;
    __syncthreads();
    tmp[tid] += t;
    __syncthreads();
  }
  if (tid < nb) bsums[tid] = tmp[tid] - v;
  if (tid == 255) bsums[nb] = tmp[255];
}

__global__ void k_scan_add(int* row_ptr, int* cursor, const int* __restrict__ bsums, int N, int nb) {
  int i = blockIdx.x * blockDim.x + threadIdx.x;
  if (i < N) {
    int v = row_ptr[i] + bsums[i >> 10];
    row_ptr[i] = v;
    cursor[i] = v;
  } else if (i == N) {
    row_ptr[N] = bsums[nb];
  }
}

__global__ void k_scatter(const int* __restrict__ ei, int* cursor, int* col, int E, int N) {
  int t = blockIdx.x * blockDim.x + threadIdx.x;
  if (t >= E + N) return;
  int s, d;
  if (t < E) { s = ei[t]; d = ei[E + t]; }
  else       { s = d = t - E; }
  int pos = atomicAdd(&cursor[d], 1);
  col[pos] = s;
}

// ---------------- encoder GEMM (N x 16 @ 16 x 128) + alpha epilogue ----------------
__global__ __launch_bounds__(256) void k_gemm_enc(
    const float* __restrict__ x, const float* __restrict__ W,
    const float* __restrict__ a_src, const float* __restrict__ a_dst,
    __half* __restrict__ gh, float* __restrict__ as_out, float* __restrict__ ad_out,
    int N) {
  const int K = 16, KP = 20;
  __shared__ float Wl[16 * 128];
  __shared__ float xl[64 * 20];
  int tid = threadIdx.x;
  int n0 = blockIdx.x * 64;

  for (int i = tid * 4; i < (K << 6); i += 1024) {
    int row = i >> 4;
    int c = i & 15;
    float4 v = make_float4(0.f, 0.f, 0.f, 0.f);
    if (n0 + row < N) v = *(const float4*)(x + (size_t)(n0 + row) * K + c);
    *(float4*)(xl + row * KP + c) = v;
  }
  for (int i = tid * 4; i < 2048; i += 1024)
    *(float4*)(Wl + i) = *(const float4*)(W + i);
  __syncthreads();

  int ng = tid >> 4, jg = tid & 15;
  int jlo = jg * 4, jhi = 64 + jg * 4;
  float alo[4][4] = {}, ahi[4][4] = {};
  #pragma unroll 4
  for (int kk = 0; kk < K; ++kk) {
    const float4 wlo = *(const float4*)(Wl + (kk << 7) + jlo);
    const float4 whi = *(const float4*)(Wl + (kk << 7) + jhi);
    const float* xr = xl + (ng * 4) * KP + kk;
    #pragma unroll
    for (int i = 0; i < 4; ++i) {
      float xv = xr[i * KP];
      alo[i][0] += xv * wlo.x; alo[i][1] += xv * wlo.y;
      alo[i][2] += xv * wlo.z; alo[i][3] += xv * wlo.w;
      ahi[i][0] += xv * whi.x; ahi[i][1] += xv * whi.y;
      ahi[i][2] += xv * whi.z; ahi[i][3] += xv * whi.w;
    }
  }

  int hlo = jg >> 2, hhi = 4 + (jg >> 2), off4 = (jg & 3) * 4;
  #pragma unroll
  for (int i = 0; i < 4; ++i) {
    int n = n0 + ng * 4 + i;
    if (n >= N) break;
    H4 plo = { __floats2half2_rn(alo[i][0], alo[i][1]), __floats2half2_rn(alo[i][2], alo[i][3]) };
    H4 phi = { __floats2half2_rn(ahi[i][0], ahi[i][1]), __floats2half2_rn(ahi[i][2], ahi[i][3]) };
    *(H4*)(gh + (size_t)n * 128 + jlo) = plo;
    *(H4*)(gh + (size_t)n * 128 + jhi) = phi;
    float ps_lo = 0.f, pd_lo = 0.f, ps_hi = 0.f, pd_hi = 0.f;
    #pragma unroll
    for (int t = 0; t < 4; ++t) {
      ps_lo += alo[i][t] * a_src[hlo * 16 + off4 + t];
      pd_lo += alo[i][t] * a_dst[hlo * 16 + off4 + t];
      ps_hi += ahi[i][t] * a_src[hhi * 16 + off4 + t];
      pd_hi += ahi[i][t] * a_dst[hhi * 16 + off4 + t];
    }
    ps_lo += __shfl_xor(ps_lo, 1); ps_lo += __shfl_xor(ps_lo, 2);
    pd_lo += __shfl_xor(pd_lo, 1); pd_lo += __shfl_xor(pd_lo, 2);
    ps_hi += __shfl_xor(ps_hi, 1); ps_hi += __shfl_xor(ps_hi, 2);
    pd_hi += __shfl_xor(pd_hi, 1); pd_hi += __shfl_xor(pd_hi, 2);
    if ((jg & 3) == 0) {
      as_out[n * 8 + hlo] = ps_lo; ad_out[n * 8 + hlo] = pd_lo;
      as_out[n * 8 + hhi] = ps_hi; ad_out[n * 8 + hhi] = pd_hi;
    }
  }
}

// ---------------- hidden GEMM (N x 128 @ 128 x 128), k-major x in LDS ----------------
__global__ __launch_bounds__(256) void k_gemm_hid(
    const float* __restrict__ x, const float* __restrict__ W,
    const float* __restrict__ a_src, const float* __restrict__ a_dst,
    __half* __restrict__ gh, float* __restrict__ as_out, float* __restrict__ ad_out,
    int N) {
  __shared__ float xlT[32][65];
  __shared__ float Wl[32][128];
  int tid = threadIdx.x;
  int n0 = blockIdx.x * 64;
  int ng = tid >> 4, jg = tid & 15;
  float acc[4][8] = {};

  for (int kb = 0; kb < 128; kb += 32) {
    __syncthreads();
    #pragma unroll
    for (int f = tid; f < 1024; f += 256)
      *(float4*)(&Wl[f >> 5][(f & 31) * 4]) =
          *(const float4*)(W + (size_t)(kb + (f >> 5)) * 128 + (f & 31) * 4);
    #pragma unroll
    for (int f = tid; f < 512; f += 256) {
      int row = f >> 3, c = (f & 7) * 4;
      float4 v = make_float4(0.f, 0.f, 0.f, 0.f);
      if (n0 + row < N) v = *(const float4*)(x + (size_t)(n0 + row) * 128 + kb + c);
      xlT[c][row] = v.x; xlT[c + 1][row] = v.y; xlT[c + 2][row] = v.z; xlT[c + 3][row] = v.w;
    }
    __syncthreads();
    #pragma unroll 4
    for (int kk = 0; kk < 32; ++kk) {
      const float4 av  = *(const float4*)(&xlT[kk][ng * 4]);
      const float4 wlo = *(const float4*)(&Wl[kk][jg * 4]);
      const float4 whi = *(const float4*)(&Wl[kk][64 + jg * 4]);
      const float an[4] = {av.x, av.y, av.z, av.w};
      #pragma unroll
      for (int i = 0; i < 4; ++i) {
        acc[i][0] += an[i] * wlo.x; acc[i][1] += an[i] * wlo.y;
        acc[i][2] += an[i] * wlo.z; acc[i][3] += an[i] * wlo.w;
        acc[i][4] += an[i] * whi.x; acc[i][5] += an[i] * whi.y;
        acc[i][6] += an[i] * whi.z; acc[i][7] += an[i] * whi.w;
      }
    }
  }

  int hlo = jg >> 2, hhi = 4 + (jg >> 2), off4 = (jg & 3) * 4;
  int jlo = jg * 4, jhi = 64 + jg * 4;
  #pragma unroll
  for (int i = 0; i < 4; ++i) {
    int n = n0 + ng * 4 + i;
    if (n >= N) break;
    H4 plo = { __floats2half2_rn(acc[i][0], acc[i][1]), __floats2half2_rn(acc[i][2], acc[i][3]) };
    H4 phi = { __floats2half2_rn(acc[i][4], acc[i][5]), __floats2half2_rn(acc[i][6], acc[i][7]) };
    *(H4*)(gh + (size_t)n * 128 + jlo) = plo;
    *(H4*)(gh + (size_t)n * 128 + jhi) = phi;
    float ps_lo = 0.f, pd_lo = 0.f, ps_hi = 0.f, pd_hi = 0.f;
    #pragma unroll
    for (int t = 0; t < 4; ++t) {
      ps_lo += acc[i][t]     * a_src[hlo * 16 + off4 + t];
      pd_lo += acc[i][t]     * a_dst[hlo * 16 + off4 + t];
      ps_hi += acc[i][4 + t] * a_src[hhi * 16 + off4 + t];
      pd_hi += acc[i][4 + t] * a_dst[hhi * 16 + off4 + t];
    }
    ps_lo += __shfl_xor(ps_lo, 1); ps_lo += __shfl_xor(ps_lo, 2);
    pd_lo += __shfl_xor(pd_lo, 1); pd_lo += __shfl_xor(pd_lo, 2);
    ps_hi += __shfl_xor(ps_hi, 1); ps_hi += __shfl_xor(ps_hi, 2);
    pd_hi += __shfl_xor(pd_hi, 1); pd_hi += __shfl_xor(pd_hi, 2);
    if ((jg & 3) == 0) {
      as_out[n * 8 + hlo] = ps_lo; ad_out[n * 8 + hlo] = pd_lo;
      as_out[n * 8 + hhi] = ps_hi; ad_out[n * 8 + hhi] = pd_hi;
    }
  }
}

// ---------------- aggregation v4, H=8 C=16, fp16 feature gather ----------------
// one wave/node. Phase 1: logits -> LDS + per-head max; convert to w=exp(e-m)
// + denominator. Phase 3: quarter-wave per edge (16 lanes x 16 B = 256 B row),
// 4 edges per wave-instr, 8 edges per unrolled iter; reduce shfl_xor(16,32).
__global__ __launch_bounds__(256) void k_agg128(
    const int* __restrict__ row_ptr, const int* __restrict__ col,
    const float* __restrict__ as, const float* __restrict__ ad,
    const __half* __restrict__ gh, const float* __restrict__ bias,
    float* __restrict__ out, int N, int act) {
  __shared__ float wbuf[4][MAXD * 8];
  int wid = threadIdx.x >> 6;
  int lane = threadIdx.x & 63;
  float* wp = wbuf[wid];
  int n = blockIdx.x * 4 + wid;
  bool active = n < N;
  int nc = active ? n : 0;
  int s0 = active ? row_ptr[nc] : 0;
  int s1 = active ? row_ptr[nc + 1] : 0;
  int deg = s1 - s0;
  int cap = deg < MAXD ? deg : MAXD;
  int capk = s0 + cap;

  // phase 1: (ch = lane>>3 edge-stride, hh = lane&7 head)
  int hh = lane & 7, ch = lane >> 3;
  float adv = ad[nc * 8 + hh];
  float mx = -FLT_MAX;
  for (int k = s0 + ch; k < s1; k += 8) {
    int s = col[k];
    float e = lrelu(as[s * 8 + hh] + adv, NEG_ATT);
    int idx = k - s0;
    if (idx < MAXD) wp[idx * 8 + hh] = e;
    mx = fmaxf(mx, e);
  }
  #pragma unroll
  for (int off = 8; off < 64; off <<= 1) mx = fmaxf(mx, __shfl_xor(mx, off));

  float den = 0.f;
  for (int idx = ch; idx < cap; idx += 8) {
    float w = __expf(wp[idx * 8 + hh] - mx);
    wp[idx * 8 + hh] = w;
    den += w;
  }
  for (int k = s0 + MAXD + ch; k < s1; k += 8) {  // beyond-cap (virtually never)
    int s = col[k];
    den += __expf(lrelu(as[s * 8 + hh] + adv, NEG_ATT) - mx);
  }
  #pragma unroll
  for (int off = 8; off < 64; off <<= 1) den += __shfl_xor(den, off);

  __syncthreads();  // wp read cross-lane below

  // phase 3: quarter-wave q handles edges b+q; lane owns 8 halves c0..c0+7
  int q = lane >> 4, l16 = lane & 15;
  int c0 = l16 * 8, hq = l16 >> 1;
  float mxq = __shfl(mx, hq);
  float denq = __shfl(den, hq);
  float t0 = 0.f, t1 = 0.f, t2 = 0.f, t3 = 0.f, t4 = 0.f, t5 = 0.f, t6 = 0.f, t7 = 0.f;
  const __half* gq = gh + c0;
  int b = s0;
  for (; b + 8 <= capk; b += 8) {   // 8 edges / wave iter, 2 gathers in flight / lane
    int e0 = b + q, e1 = b + 4 + q;
    int sa = col[e0], sb = col[e1];
    float wa = wp[(e0 - s0) * 8 + hq], wb = wp[(e1 - s0) * 8 + hq];
    H8 ha = *(const H8*)(gq + (size_t)sa * 128);
    H8 hb = *(const H8*)(gq + (size_t)sb * 128);
    float2 f;
    f = __half22float2(ha.a); t0 += wa * f.x; t1 += wa * f.y;
    f = __half22float2(ha.b); t2 += wa * f.x; t3 += wa * f.y;
    f = __half22float2(ha.c); t4 += wa * f.x; t5 += wa * f.y;
    f = __half22float2(ha.d); t6 += wa * f.x; t7 += wa * f.y;
    f = __half22float2(hb.a); t0 += wb * f.x; t1 += wb * f.y;
    f = __half22float2(hb.b); t2 += wb * f.x; t3 += wb * f.y;
    f = __half22float2(hb.c); t4 += wb * f.x; t5 += wb * f.y;
    f = __half22float2(hb.d); t6 += wb * f.x; t7 += wb * f.y;
  }
  for (; b + 4 <= capk; b += 4) {   // 4 edges / wave iter
    int e0 = b + q;
    int sa = col[e0];
    float wa = wp[(e0 - s0) * 8 + hq];
    H8 ha = *(const H8*)(gq + (size_t)sa * 128);
    float2 f;
    f = __half22float2(ha.a); t0 += wa * f.x; t1 += wa * f.y;
    f = __half22float2(ha.b); t2 += wa * f.x; t3 += wa * f.y;
    f = __half22float2(ha.c); t4 += wa * f.x; t5 += wa * f.y;
    f = __half22float2(ha.d); t6 += wa * f.x; t7 += wa * f.y;
  }
  if (b + q < capk) {               // masked remainder (<4 edges)
    int e0 = b + q;
    int sa = col[e0];
    float wa = wp[(e0 - s0) * 8 + hq];
    H8 ha = *(const H8*)(gq + (size_t)sa * 128);
    float2 f;
    f = __half22float2(ha.a); t0 += wa * f.x; t1 += wa * f.y;
    f = __half22float2(ha.b); t2 += wa * f.x; t3 += wa * f.y;
    f = __half22float2(ha.c); t4 += wa * f.x; t5 += wa * f.y;
    f = __half22float2(ha.d); t6 += wa * f.x; t7 += wa * f.y;
  }
  for (int k = capk + q; k < s1; k += 4) {  // beyond-cap (virtually never)
    int s = col[k];
    float w = __expf(lrelu(as[s * 8 + hq] + ad[nc * 8 + hq], NEG_ATT) - mxq);
    H8 ha = *(const H8*)(gq + (size_t)s * 128);
    float2 f;
    f = __half22float2(ha.a); t0 += w * f.x; t1 += w * f.y;
    f = __half22float2(ha.b); t2 += w * f.x; t3 += w * f.y;
    f = __half22float2(ha.c); t4 += w * f.x; t5 += w * f.y;
    f = __half22float2(ha.d); t6 += w * f.x; t7 += w * f.y;
  }
  t0 += __shfl_xor(t0, 16); t0 += __shfl_xor(t0, 32);
  t1 += __shfl_xor(t1, 16); t1 += __shfl_xor(t1, 32);
  t2 += __shfl_xor(t2, 16); t2 += __shfl_xor(t2, 32);
  t3 += __shfl_xor(t3, 16); t3 += __shfl_xor(t3, 32);
  t4 += __shfl_xor(t4, 16); t4 += __shfl_xor(t4, 32);
  t5 += __shfl_xor(t5, 16); t5 += __shfl_xor(t5, 32);
  t6 += __shfl_xor(t6, 16); t6 += __shfl_xor(t6, 32);
  t7 += __shfl_xor(t7, 16); t7 += __shfl_xor(t7, 32);
  if (active && q == 0) {
    float inv = 1.f / denq;
    const float4 b0 = *(const float4*)(bias + c0);
    const float4 b1 = *(const float4*)(bias + c0 + 4);
    float o0 = t0 * inv + b0.x, o1 = t1 * inv + b0.y;
    float o2 = t2 * inv + b0.z, o3 = t3 * inv + b0.w;
    float o4 = t4 * inv + b1.x, o5 = t5 * inv + b1.y;
    float o6 = t6 * inv + b1.z, o7 = t7 * inv + b1.w;
    if (act) {
      o0 = lrelu(o0, NEG_ACT); o1 = lrelu(o1, NEG_ACT);
      o2 = lrelu(o2, NEG_ACT); o3 = lrelu(o3, NEG_ACT);
      o4 = lrelu(o4, NEG_ACT); o5 = lrelu(o5, NEG_ACT);
      o6 = lrelu(o6, NEG_ACT); o7 = lrelu(o7, NEG_ACT);
    }
    *(float4*)(out + (size_t)n * 128 + c0)     = make_float4(o0, o1, o2, o3);
    *(float4*)(out + (size_t)n * 128 + c0 + 4) = make_float4(o4, o5, o6, o7);
  }
}

// ---------------- decoder: GEMM 128->3, pack (h0,h1,h2,alpha_src) ----------------
__global__ __launch_bounds__(256) void k_dec_gemm(
    const float* __restrict__ h, const float* __restrict__ Wd,
    const float* __restrict__ asd, const float* __restrict__ add,
    float4* __restrict__ g4, float* __restrict__ ad_out, int N) {
  __shared__ float Wl[384];
  int tid = threadIdx.x;
  for (int i = tid; i < 384; i += 256) Wl[i] = Wd[i];
  __syncthreads();
  int n = blockIdx.x * 256 + tid;
  if (n >= N) return;
  const float* hr = h + (size_t)n * 128;
  float a0 = 0.f, a1 = 0.f, a2 = 0.f;
  #pragma unroll 4
  for (int k = 0; k < 128; k += 4) {
    float4 xv = *(const float4*)(hr + k);
    a0 += xv.x * Wl[k * 3]     + xv.y * Wl[(k + 1) * 3]     + xv.z * Wl[(k + 2) * 3]     + xv.w * Wl[(k + 3) * 3];
    a1 += xv.x * Wl[k * 3 + 1] + xv.y * Wl[(k + 1) * 3 + 1] + xv.z * Wl[(k + 2) * 3 + 1] + xv.w * Wl[(k + 3) * 3 + 1];
    a2 += xv.x * Wl[k * 3 + 2] + xv.y * Wl[(k + 1) * 3 + 2] + xv.z * Wl[(k + 2) * 3 + 2] + xv.w * Wl[(k + 3) * 3 + 2];
  }
  float as_n = a0 * asd[0] + a1 * asd[1] + a2 * asd[2];
  g4[n] = make_float4(a0, a1, a2, as_n);
  ad_out[n] = a0 * add[0] + a1 * add[1] + a2 * add[2];
}

// ---------------- decoder aggregation, H=1 C=3, one-pass online softmax ----------------
__global__ __launch_bounds__(256) void k_dec_agg(
    const int* __restrict__ row_ptr, const int* __restrict__ col,
    const float* __restrict__ ad, const float4* __restrict__ g4,
    const float* __restrict__ b, float* __restrict__ out, int N) {
  int n = blockIdx.x * blockDim.x + threadIdx.x;
  if (n >= N) return;
  int s0 = row_ptr[n], s1 = row_ptr[n + 1];
  float adv = ad[n];
  float m = -FLT_MAX, den = 0.f, A0 = 0.f, A1 = 0.f, A2 = 0.f;
  int k = s0;
  for (; k + 4 <= s1; k += 4) {
    int sa = col[k], sb = col[k + 1], sc = col[k + 2], sd = col[k + 3];
    float4 v0 = g4[sa], v1 = g4[sb], v2 = g4[sc], v3 = g4[sd];
    #pragma unroll
    for (int j = 0; j < 4; ++j) {
      float4 v = (j == 0) ? v0 : (j == 1) ? v1 : (j == 2) ? v2 : v3;
      float e = lrelu(v.w + adv, NEG_ATT);
      float mn = fmaxf(m, e);
      float corr = __expf(m - mn);
      float w = __expf(e - mn);
      den = den * corr + w;
      A0 = A0 * corr + w * v.x;
      A1 = A1 * corr + w * v.y;
      A2 = A2 * corr + w * v.z;
      m = mn;
    }
  }
  for (; k < s1; ++k) {
    float4 v = g4[col[k]];
    float e = lrelu(v.w + adv, NEG_ATT);
    float mn = fmaxf(m, e);
    float corr = __expf(m - mn);
    float w = __expf(e - mn);
    den = den * corr + w;
    A0 = A0 * corr + w * v.x;
    A1 = A1 * corr + w * v.y;
    A2 = A2 * corr + w * v.z;
    m = mn;
  }
  float inv = 1.f / den;
  out[(size_t)n * 3]     = A0 * inv + b[0];
  out[(size_t)n * 3 + 1] = A1 * inv + b[1];
  out[(size_t)n * 3 + 2] = A2 * inv + b[2];
}

// ---------------- host ----------------
extern "C" void kernel_launch(void* const* d_in, const int* in_sizes, int n_in,
                              void* d_out, int out_size, void* d_ws, size_t ws_size,
                              hipStream_t stream) {
  const float* x      = (const float*)d_in[0];
  const int*   ei     = (const int*)d_in[1];
  const float* enc_W  = (const float*)d_in[2];
  const float* enc_as = (const float*)d_in[3];
  const float* enc_ad = (const float*)d_in[4];
  const float* enc_b  = (const float*)d_in[5];
  const float* hid_W  = (const float*)d_in[6];
  const float* hid_as = (const float*)d_in[7];
  const float* hid_ad = (const float*)d_in[8];
  const float* hid_b  = (const float*)d_in[9];
  const float* dec_W  = (const float*)d_in[10];
  const float* dec_as = (const float*)d_in[11];
  const float* dec_ad = (const float*)d_in[12];
  const float* dec_b  = (const float*)d_in[13];

  const int N = in_sizes[0] / 16;
  const int E = in_sizes[1] / 2;
  const int L = in_sizes[6] / (128 * 128);

  float*  f       = (float*)d_ws;
  float*  hA      = f;                                   // N*128 f32
  __half* gh      = (__half*)(f + (size_t)N * 128);      // N*128 f16 (= N*64 f32 slots)
  float*  as_buf  = f + (size_t)N * 192;
  float*  ad_buf  = as_buf + (size_t)N * 8;
  float4* g4      = (float4*)(ad_buf + (size_t)N * 8);   // N float4
  int*    row_ptr = (int*)(g4 + N);
  int*    degcur  = row_ptr + (N + 1);
  int*    colb    = degcur + (N + 1);
  int*    bsums   = colb + (E + N);

  const int nb = (N + 1023) / 1024;

  k_init_deg<<<dim3((N + 255) / 256), dim3(256), 0, stream>>>(degcur, N);
  k_count<<<dim3((E + 255) / 256), dim3(256), 0, stream>>>(ei, degcur, E);
  k_scan_block<<<dim3(nb), dim3(1024), 0, stream>>>(degcur, row_ptr, bsums, N);
  k_scan_sums<<<dim3(1), dim3(256), 0, stream>>>(bsums, nb);
  k_scan_add<<<dim3((N + 256) / 256), dim3(256), 0, stream>>>(row_ptr, degcur, bsums, N, nb);
  k_scatter<<<dim3((E + N + 255) / 256), dim3(256), 0, stream>>>(ei, degcur, colb, E, N);

  const dim3 gGemm((N + 63) / 64), b256(256);
  const dim3 gAgg((N + 3) / 4);
  const dim3 gNode((N + 255) / 256);

  k_gemm_enc<<<gGemm, b256, 0, stream>>>(x, enc_W, enc_as, enc_ad, gh, as_buf, ad_buf, N);
  k_agg128<<<gAgg, b256, 0, stream>>>(row_ptr, colb, as_buf, ad_buf, gh, enc_b, hA, N, 1);

  for (int l = 0; l < L; ++l) {
    k_gemm_hid<<<gGemm, b256, 0, stream>>>(hA, hid_W + (size_t)l * 128 * 128,
                                           hid_as + (size_t)l * 128, hid_ad + (size_t)l * 128,
                                           gh, as_buf, ad_buf, N);
    k_agg128<<<gAgg, b256, 0, stream>>>(row_ptr, colb, as_buf, ad_buf, gh,
                                        hid_b + (size_t)l * 128, hA, N, 0);
  }

  k_dec_gemm<<<gNode, b256, 0, stream>>>(hA, dec_W, dec_as, dec_ad, g4, ad_buf, N);
  k_dec_agg<<<gNode, b256, 0, stream>>>(row_ptr, colb, ad_buf, g4, dec_b,
                                        (float*)d_out, N);
}